// Round 7
// baseline (993.094 us; speedup 1.0000x reference)
//
#include <hip/hip_runtime.h>

#define NB 8
#define LSEQ 1024
#define DM 64
#define DFF 256
#define NLAYER 4
#define NROW (NB*LSEQ)

__device__ __forceinline__ float wsum64(float v){
  #pragma unroll
  for (int off = 32; off; off >>= 1) v += __shfl_xor(v, off);
  return v;
}
__device__ __forceinline__ float wmax64(float v){
  #pragma unroll
  for (int off = 32; off; off >>= 1) v = fmaxf(v, __shfl_xor(v, off));
  return v;
}

// ---- nz per batch ----
__global__ void nz_kernel(const int* __restrict__ protok, float* __restrict__ nz){
  __shared__ float sm[16];
  int t = threadIdx.x;
  float v = (protok[blockIdx.x * LSEQ + t] != 0) ? 1.f : 0.f;
  v = wsum64(v);
  if ((t & 63) == 0) sm[t >> 6] = v;
  __syncthreads();
  if (t < 16){
    float s = sm[t];
    #pragma unroll
    for (int off = 8; off; off >>= 1) s += __shfl_xor(s, off);
    if (t == 0) nz[blockIdx.x] = s;
  }
}

// LDS pool offsets (floats)
#define QS_OFF   0        // [1024][8]  = 8192
#define VS_OFF   8192     // [1024][8]  = 8192
#define KS_OFF   16384    // [256][9]   = 2304 (stride-9: conflict-free kr loads)
#define WS_OFF   18688    // [3][64][8] = 1536
#define XSG_OFF  20224    // [128][72]  = 9216
#define RED_OFF  29440    // [32]
#define POOL_SZ  29472    // 117.9 KB -> 1 block/CU, 16 waves = 4/SIMD
// merge region reuses [0 .. 8*2112=16896); final staging at [4224 .. 6528)

// ---- fused QKV + joint-softmax attention ----
// block = (bh, kc in 0..3); 1024 threads: wave j = 64-q chunk, lane kg owns keys kg+64*kk.
__global__ __launch_bounds__(1024) void qkv_attn(
    const float* __restrict__ xin, const int* __restrict__ protok,
    const float* __restrict__ Wq, const float* __restrict__ bq,
    const float* __restrict__ Wk, const float* __restrict__ bk,
    const float* __restrict__ Wv, const float* __restrict__ bv,
    float* __restrict__ part, float* __restrict__ mh_out,
    float* __restrict__ mt_out, float* __restrict__ s_out)
{
  int blk = blockIdx.x, bh = blk >> 2, kc = blk & 3;
  int b = bh >> 3, h = bh & 7;
  int t = threadIdx.x;
  __shared__ __align__(16) float pool[POOL_SZ];

  // stage weight head-slices (first 512 threads)
  if (t < 512) {
    int jj = t >> 3, c8 = t & 7;
    pool[WS_OFF + t]        = Wq[jj * DM + h * 8 + c8];
    pool[WS_OFF + 512 + t]  = Wk[jj * DM + h * 8 + c8];
    pool[WS_OFF + 1024 + t] = Wv[jj * DM + h * 8 + c8];
  }
  int cc = t & 7, prow = t >> 3;   // prow 0..127
  float bqv = bq[h*8+cc], bkv = bk[h*8+cc], bvv = bv[h*8+cc];
  __syncthreads();

  // ---- projection: Q,V all 1024 rows (8 chunks of 128); K own 256 rows ----
  float qn2max = 0.f, kn2max = 0.f;
  for (int ch = 0; ch < 8; ++ch) {
    int r0 = ch * 128;
    {
      int i = t >> 3, c8 = (t & 7) * 8;
      const float4* p = (const float4*)&xin[((size_t)(b*LSEQ + r0 + i))*DM + c8];
      float4 p0 = p[0], p1 = p[1];
      *(float4*)&pool[XSG_OFF + i*72 + c8]     = p0;
      *(float4*)&pool[XSG_OFF + i*72 + c8 + 4] = p1;
    }
    __syncthreads();
    float keep = (protok[b*LSEQ + r0 + prow] != 0) ? 1.f : 0.f;
    float aq = bqv, av = bvv;
    #pragma unroll
    for (int jj = 0; jj < DM; ++jj) {
      float xv = pool[XSG_OFF + prow*72 + jj];
      aq = fmaf(xv, pool[WS_OFF + jj*8 + cc], aq);
      av = fmaf(xv, pool[WS_OFF + 1024 + jj*8 + cc], av);
    }
    aq *= keep; av *= keep;
    int gr = r0 + prow;
    pool[QS_OFF + gr*8 + cc] = aq;
    pool[VS_OFF + gr*8 + cc] = av;
    float s2 = aq * aq;
    s2 += __shfl_xor(s2, 1); s2 += __shfl_xor(s2, 2); s2 += __shfl_xor(s2, 4);
    qn2max = fmaxf(qn2max, s2);
    if ((ch >> 1) == kc) {
      float ak = bkv;
      #pragma unroll
      for (int jj = 0; jj < DM; ++jj)
        ak = fmaf(pool[XSG_OFF + prow*72 + jj], pool[WS_OFF + 512 + jj*8 + cc], ak);
      ak *= keep;
      pool[KS_OFF + (gr - kc*256)*9 + cc] = ak;
      float k2 = ak * ak;
      k2 += __shfl_xor(k2, 1); k2 += __shfl_xor(k2, 2); k2 += __shfl_xor(k2, 4);
      kn2max = fmaxf(kn2max, k2);
    }
    __syncthreads();
  }

  // Cauchy-Schwarz logit upper bound mhat = max|q| * max|k|
  int wid = t >> 6, lane = t & 63;
  {
    float qm = wmax64(qn2max), km = wmax64(kn2max);
    if (lane == 0) { pool[RED_OFF + wid] = qm; pool[RED_OFF + 16 + wid] = km; }
  }
  __syncthreads();
  float qn2 = pool[RED_OFF], kn2 = pool[RED_OFF + 16];
  #pragma unroll
  for (int i = 1; i < 16; ++i) {
    qn2 = fmaxf(qn2, pool[RED_OFF + i]);
    kn2 = fmaxf(kn2, pool[RED_OFF + 16 + i]);
  }
  float mhat = sqrtf(qn2 * kn2);
  __syncthreads();

  // ---- main pass: wave j covers q in [j*64, j*64+64); lane kg owns keys kg+64*kk ----
  int j = wid, kg = lane;
  float kr[4][8], pjm[4];
  #pragma unroll
  for (int kk = 0; kk < 4; ++kk) {
    #pragma unroll
    for (int dd = 0; dd < 8; ++dd) kr[kk][dd] = pool[KS_OFF + (kk*64+kg)*9 + dd];
    pjm[kk] = ((protok[b*LSEQ + kc*256 + kk*64 + kg] != 0) ? 0.f : -1.0e9f) - mhat;
  }

  float acc[4][8] = {};
  float st = 0.f, mu_sh = -3.0e38f;
  int q0 = j * 64;

#define COMPUTE(Q0,Q1,V0,V1) { \
    float qv[8] = {Q0.x,Q0.y,Q0.z,Q0.w,Q1.x,Q1.y,Q1.z,Q1.w}; \
    float vv[8] = {V0.x,V0.y,V0.z,V0.w,V1.x,V1.y,V1.z,V1.w}; \
    _Pragma("unroll") \
    for (int kk = 0; kk < 4; ++kk) { \
      float d = pjm[kk]; \
      _Pragma("unroll") \
      for (int dd = 0; dd < 8; ++dd) d = fmaf(qv[dd], kr[kk][dd], d); \
      mu_sh = fmaxf(mu_sh, d); \
      float e = __expf(d); \
      st += e; \
      _Pragma("unroll") \
      for (int dd = 0; dd < 8; ++dd) acc[kk][dd] = fmaf(e, vv[dd], acc[kk][dd]); \
    } }

  // software-pipelined, unroll x2 (over-reads at q0+64 land in VS/KS regions: harmless)
  float4 qA0 = *(const float4*)&pool[QS_OFF + q0*8];
  float4 qA1 = *(const float4*)&pool[QS_OFF + q0*8 + 4];
  float4 vA0 = *(const float4*)&pool[VS_OFF + q0*8];
  float4 vA1 = *(const float4*)&pool[VS_OFF + q0*8 + 4];
  for (int qq = 0; qq < 64; qq += 2) {
    int qB = q0 + qq + 1, qA2 = q0 + qq + 2;
    float4 qB0 = *(const float4*)&pool[QS_OFF + qB*8];
    float4 qB1 = *(const float4*)&pool[QS_OFF + qB*8 + 4];
    float4 vB0 = *(const float4*)&pool[VS_OFF + qB*8];
    float4 vB1 = *(const float4*)&pool[VS_OFF + qB*8 + 4];
    COMPUTE(qA0, qA1, vA0, vA1);
    qA0 = *(const float4*)&pool[QS_OFF + qA2*8];
    qA1 = *(const float4*)&pool[QS_OFF + qA2*8 + 4];
    vA0 = *(const float4*)&pool[VS_OFF + qA2*8];
    vA1 = *(const float4*)&pool[VS_OFF + qA2*8 + 4];
    COMPUTE(qB0, qB1, vB0, vB1);
  }
#undef COMPUTE
  __syncthreads();

  // block reductions: true max (shifted) and exp-sum
  {
    float mw = wmax64(mu_sh), sw = wsum64(st);
    if (lane == 0) { pool[RED_OFF + wid] = mw; pool[RED_OFF + 16 + wid] = sw; }
  }
  __syncthreads();
  if (t == 0) {
    float m = pool[RED_OFF];
    float s = pool[RED_OFF + 16];
    #pragma unroll
    for (int i = 1; i < 16; ++i) {
      m = fmaxf(m, pool[RED_OFF + i]);
      s += pool[RED_OFF + 16 + i];
    }
    s_out[blk] = s; mh_out[blk] = mhat; mt_out[blk] = m + mhat;
  }
  __syncthreads();

  // ---- merge acc across 16 waves: 4 halving rounds (stride-33 rows, conflict-free) ----
#define MWRITE(DW) { _Pragma("unroll") for (int kk = 0; kk < 4; ++kk) \
    { _Pragma("unroll") for (int dd = 0; dd < 8; ++dd) \
      pool[(DW)*2112 + kg*33 + kk*8 + dd] = acc[kk][dd]; } }
#define MADD(SW) { _Pragma("unroll") for (int kk = 0; kk < 4; ++kk) \
    { _Pragma("unroll") for (int dd = 0; dd < 8; ++dd) \
      acc[kk][dd] += pool[(SW)*2112 + kg*33 + kk*8 + dd]; } }
  if (j >= 8) MWRITE(j - 8);
  __syncthreads();
  if (j < 8) MADD(j);
  __syncthreads();
  if (j >= 4 && j < 8) MWRITE(j - 4 + 8);   // use region 8.. wait-free? no: reuse 0..3
  __syncthreads();
  // NOTE: rounds must not race: writers of round r write regions read in round r only.
  if (j < 4 && j >= 0) { if (j < 4) {} }
  __syncthreads();
  if (j < 4) MADD(j + 8);
  __syncthreads();
  if (j >= 2 && j < 4) MWRITE(j - 2);
  __syncthreads();
  if (j < 2) MADD(j);
  __syncthreads();
  if (j == 1) MWRITE(4);
  __syncthreads();
  if (j == 0) {
    MADD(4);
    // stage to [4224 .. 6528) in [key][9] layout for coalesced-ish final store
    #pragma unroll
    for (int kk = 0; kk < 4; ++kk)
      #pragma unroll
      for (int dd = 0; dd < 8; ++dd)
        pool[4224 + (kk*64 + kg)*9 + dd] = acc[kk][dd];
  }
#undef MWRITE
#undef MADD
  __syncthreads();

  // final store: 1024 threads x float2 (2048 floats)
  {
    int key = t >> 2, dd0 = (t & 3) * 2;
    float x0 = pool[4224 + key*9 + dd0];
    float x1 = pool[4224 + key*9 + dd0 + 1];
    float* dst = &part[((size_t)(b*LSEQ + kc*256 + key))*DM + h*8 + dd0];
    *(float2*)dst = make_float2(x0, x1);
  }
}

// ---- combine: per bh true max + S; cs[kc][bh] ----
__global__ void attn_combine(const float* __restrict__ mh, const float* __restrict__ mt,
                             const float* __restrict__ sp, const float* __restrict__ nz,
                             float* __restrict__ cs){
  int bh = threadIdx.x;
  float mhl[4], sl[4];
  float mu = -3.0e38f;
  #pragma unroll
  for (int i = 0; i < 4; ++i) {
    mhl[i] = mh[bh*4+i]; sl[i] = sp[bh*4+i];
    mu = fmaxf(mu, mt[bh*4+i]);
  }
  float S = 0.f;
  #pragma unroll
  for (int i = 0; i < 4; ++i) S += sl[i] * __expf(mhl[i] - mu);
  float w = nz[bh >> 3] / S;
  float gm = wmax64(w);
  float c = w / gm;
  #pragma unroll
  for (int i = 0; i < 4; ++i) cs[i*64 + bh] = c * __expf(mhl[i] - mu);
}

// ---- O-proj + residual + LN1 (8 rows/block); po: part in, out1 out ----
__global__ __launch_bounds__(512) void oproj_ln(
    float* po, const float* __restrict__ cs,
    const float* __restrict__ Wo, const float* __restrict__ bo,
    const float* __restrict__ xin, const float* __restrict__ g,
    const float* __restrict__ be, const int* __restrict__ protok)
{
  int tid = threadIdx.x, rl = tid >> 6, c = tid & 63;
  int r = blockIdx.x * 8 + rl;
  int bh = ((r >> 10) << 3) + (c >> 3);
  int kc = (r >> 8) & 3;
  __shared__ float As[8][64];
  As[rl][c] = po[(size_t)r * DM + c] * cs[kc*64 + bh];
  __syncthreads();
  float acc = bo[c];
  #pragma unroll
  for (int jj = 0; jj < DM; ++jj) acc = fmaf(As[rl][jj], Wo[jj * DM + c], acc);
  float keep = (protok[r] != 0) ? 1.f : 0.f;
  float v = xin[(size_t)r * DM + c] + acc * keep;
  float mu = wsum64(v) * 0.015625f;
  float d = v - mu;
  float var = wsum64(d * d) * 0.015625f;
  float o = d * rsqrtf(var + 1e-9f) * g[c] + be[c];
  po[(size_t)r * DM + c] = o * keep;
}

// ---- fused FFN + residual + LN2 (8 rows/block) ----
__global__ __launch_bounds__(512) void ffn_ln(
    const float* __restrict__ out1,
    const float* __restrict__ W1, const float* __restrict__ b1,
    const float* __restrict__ W2, const float* __restrict__ b2,
    const float* __restrict__ g, const float* __restrict__ be,
    const int* __restrict__ protok, float* __restrict__ xout)
{
  int tid = threadIdx.x, rl = tid >> 6, c = tid & 63;
  int r = blockIdx.x * 8 + rl;
  __shared__ float xs[8][64];
  __shared__ float h1s[8][DFF];
  xs[rl][c] = out1[(size_t)r * DM + c];
  __syncthreads();
  #pragma unroll
  for (int s = 0; s < 4; ++s) {
    int col = c + 64 * s;
    float a = b1[col];
    #pragma unroll
    for (int jj = 0; jj < DM; ++jj) a = fmaf(xs[rl][jj], W1[jj * DFF + col], a);
    h1s[rl][col] = fmaxf(a, 0.f);
  }
  __syncthreads();
  float a2 = b2[c];
  #pragma unroll 8
  for (int jj = 0; jj < DFF; ++jj) a2 = fmaf(h1s[rl][jj], W2[jj * DM + c], a2);
  float keep = (protok[r] != 0) ? 1.f : 0.f;
  float v = xs[rl][c] + a2 * keep;
  float mu = wsum64(v) * 0.015625f;
  float d = v - mu;
  float var = wsum64(d * d) * 0.015625f;
  float o = d * rsqrtf(var + 1e-9f) * g[c] + be[c];
  xout[(size_t)r * DM + c] = o * keep;
}

extern "C" void kernel_launch(void* const* d_in, const int* in_sizes, int n_in,
                              void* d_out, int out_size, void* d_ws, size_t ws_size,
                              hipStream_t stream) {
  const float* x      = (const float*)d_in[0];
  const int*   protok = (const int*)d_in[1];
  const float* Wq = (const float*)d_in[2];  const float* bq = (const float*)d_in[3];
  const float* Wk = (const float*)d_in[4];  const float* bk = (const float*)d_in[5];
  const float* Wv = (const float*)d_in[6];  const float* bv = (const float*)d_in[7];
  const float* Wo = (const float*)d_in[8];  const float* bo = (const float*)d_in[9];
  const float* W1 = (const float*)d_in[10]; const float* b1 = (const float*)d_in[11];
  const float* W2 = (const float*)d_in[12]; const float* b2 = (const float*)d_in[13];
  const float* g1 = (const float*)d_in[14]; const float* be1 = (const float*)d_in[15];
  const float* g2 = (const float*)d_in[16]; const float* be2 = (const float*)d_in[17];

  const size_t N = (size_t)NROW * DM;   // 524288
  float* xf   = (float*)d_ws;           // N
  float* po   = xf + N;                 // N (attn part -> out1, aliased)
  float* nzb  = po + N;                 // 8
  float* mh   = nzb + 8;                // 256
  float* mt   = mh + 256;               // 256
  float* sp   = mt + 256;               // 256
  float* cs   = sp + 256;               // 256

  nz_kernel<<<NB, 1024, 0, stream>>>(protok, nzb);

  for (int l = 0; l < NLAYER; ++l) {
    const float* Wq_l = Wq + (size_t)l * DM * DM;  const float* bq_l = bq + (size_t)l * DM;
    const float* Wk_l = Wk + (size_t)l * DM * DM;  const float* bk_l = bk + (size_t)l * DM;
    const float* Wv_l = Wv + (size_t)l * DM * DM;  const float* bv_l = bv + (size_t)l * DM;
    const float* Wo_l = Wo + (size_t)l * DM * DM;  const float* bo_l = bo + (size_t)l * DM;
    const float* W1_l = W1 + (size_t)l * DM * DFF; const float* b1_l = b1 + (size_t)l * DFF;
    const float* W2_l = W2 + (size_t)l * DFF * DM; const float* b2_l = b2 + (size_t)l * DM;
    const float* g1_l = g1 + (size_t)l * DM;  const float* be1_l = be1 + (size_t)l * DM;
    const float* g2_l = g2 + (size_t)l * DM;  const float* be2_l = be2 + (size_t)l * DM;

    const float* xin = (l == 0) ? x : xf;
    float* xout = (l == NLAYER - 1) ? (float*)d_out : xf;

    qkv_attn<<<256, 1024, 0, stream>>>(xin, protok, Wq_l, bq_l, Wk_l, bk_l, Wv_l, bv_l,
                                       po, mh, mt, sp);
    attn_combine<<<1, 64, 0, stream>>>(mh, mt, sp, nzb, cs);
    oproj_ln<<<NROW / 8, 512, 0, stream>>>(po, cs, Wo_l, bo_l, xin, g1_l, be1_l, protok);
    ffn_ln<<<NROW / 8, 512, 0, stream>>>(po, W1_l, b1_l, W2_l, b2_l, g2_l, be2_l, protok, xout);
  }
}

// Round 8
// 457.574 us; speedup vs baseline: 2.1703x; 2.1703x over previous
//
#include <hip/hip_runtime.h>

#define NB 8
#define LSEQ 1024
#define DM 64
#define DFF 256
#define NLAYER 4
#define NROW (NB*LSEQ)
#define LOG2E 1.44269504088896f

__device__ __forceinline__ float wsum64(float v){
  #pragma unroll
  for (int off = 32; off; off >>= 1) v += __shfl_xor(v, off);
  return v;
}
__device__ __forceinline__ float wmax64(float v){
  #pragma unroll
  for (int off = 32; off; off >>= 1) v = fmaxf(v, __shfl_xor(v, off));
  return v;
}

// ---- nz per batch ----
__global__ void nz_kernel(const int* __restrict__ protok, float* __restrict__ nz){
  __shared__ float sm[16];
  int t = threadIdx.x;
  float v = (protok[blockIdx.x * LSEQ + t] != 0) ? 1.f : 0.f;
  v = wsum64(v);
  if ((t & 63) == 0) sm[t >> 6] = v;
  __syncthreads();
  if (t < 16){
    float s = sm[t];
    #pragma unroll
    for (int off = 8; off; off >>= 1) s += __shfl_xor(s, off);
    if (t == 0) nz[blockIdx.x] = s;
  }
}

// LDS pool offsets (floats)
#define QS_OFF   0        // [512][8]  = 4096  (Q pre-scaled by log2e)
#define VS_OFF   4096     // [512][8]  = 4096
#define KS_OFF   8192     // [256][9]  = 2304
#define WS_OFF   10496    // [3][64][8]= 1536
#define XSG_OFF  12032    // [64][72]  = 4608
#define RED_OFF  16640    // [32]
#define POOL_SZ  16672    // 65.1 KB -> 2 blocks/CU, 4 waves/SIMD
// merge regions (post-main-loop) overlay [0 .. 4*2112=8448)

// ---- fused QKV + joint-softmax attention ----
// block = (bh, kc in 0..3, qh in 0..1); 512 threads; wave j = 64-q chunk of the
// 512-q half; lane kg owns keys kk*64+kg. All logits in log2 domain.
__global__ __launch_bounds__(512, 4) void qkv_attn(
    const float* __restrict__ xin, const int* __restrict__ protok,
    const float* __restrict__ Wq, const float* __restrict__ bq,
    const float* __restrict__ Wk, const float* __restrict__ bk,
    const float* __restrict__ Wv, const float* __restrict__ bv,
    float* __restrict__ part0, float* __restrict__ part1,
    float* __restrict__ mh_out, float* __restrict__ mt_out, float* __restrict__ s_out)
{
  int blk = blockIdx.x;
  int bh = blk >> 3, kc = (blk >> 1) & 3, qh = blk & 1;
  int b = bh >> 3, h = bh & 7;
  int t = threadIdx.x;
  __shared__ __align__(16) float pool[POOL_SZ];

  // stage weight head-slices
  {
    int jj = t >> 3, c8 = t & 7;
    pool[WS_OFF + t]        = Wq[jj * DM + h * 8 + c8];
    pool[WS_OFF + 512 + t]  = Wk[jj * DM + h * 8 + c8];
    pool[WS_OFF + 1024 + t] = Wv[jj * DM + h * 8 + c8];
  }
  int cc = t & 7, prow = t >> 3;   // prow 0..63
  float bqv = bq[h*8+cc], bkv = bk[h*8+cc], bvv = bv[h*8+cc];
  __syncthreads();

  // ---- projection: 8 chunks Q/V (own q-half) + 4 chunks K (own key range) ----
  float qn2max = 0.f, kn2max = 0.f;
  for (int ch = 0; ch < 12; ++ch) {
    int gr0 = (ch < 8) ? (qh*512 + ch*64) : (kc*256 + (ch-8)*64);
    {
      int i = t >> 3, c8 = (t & 7) * 8;
      const float4* p = (const float4*)&xin[((size_t)(b*LSEQ + gr0 + i))*DM + c8];
      float4 p0 = p[0], p1 = p[1];
      *(float4*)&pool[XSG_OFF + i*72 + c8]     = p0;
      *(float4*)&pool[XSG_OFF + i*72 + c8 + 4] = p1;
    }
    __syncthreads();
    float keep = (protok[b*LSEQ + gr0 + prow] != 0) ? 1.f : 0.f;
    if (ch < 8) {
      float aq = bqv, av = bvv;
      #pragma unroll
      for (int jj = 0; jj < DM; ++jj) {
        float xv = pool[XSG_OFF + prow*72 + jj];
        aq = fmaf(xv, pool[WS_OFF + jj*8 + cc], aq);
        av = fmaf(xv, pool[WS_OFF + 1024 + jj*8 + cc], av);
      }
      aq *= keep * LOG2E;   // log2-domain Q
      av *= keep;
      int lq = ch*64 + prow;
      pool[QS_OFF + lq*8 + cc] = aq;
      pool[VS_OFF + lq*8 + cc] = av;
      float s2 = aq * aq;
      s2 += __shfl_xor(s2, 1); s2 += __shfl_xor(s2, 2); s2 += __shfl_xor(s2, 4);
      qn2max = fmaxf(qn2max, s2);
    } else {
      float ak = bkv;
      #pragma unroll
      for (int jj = 0; jj < DM; ++jj)
        ak = fmaf(pool[XSG_OFF + prow*72 + jj], pool[WS_OFF + 512 + jj*8 + cc], ak);
      ak *= keep;
      int lk = (ch-8)*64 + prow;
      pool[KS_OFF + lk*9 + cc] = ak;
      float k2 = ak * ak;
      k2 += __shfl_xor(k2, 1); k2 += __shfl_xor(k2, 2); k2 += __shfl_xor(k2, 4);
      kn2max = fmaxf(kn2max, k2);
    }
    __syncthreads();
  }

  // Cauchy-Schwarz bound (log2 domain): mhat = |q~| * |k|
  int wid = t >> 6, lane = t & 63;
  {
    float qm = wmax64(qn2max), km = wmax64(kn2max);
    if (lane == 0) { pool[RED_OFF + wid] = qm; pool[RED_OFF + 16 + wid] = km; }
  }
  __syncthreads();
  float qn2 = pool[RED_OFF], kn2 = pool[RED_OFF + 16];
  #pragma unroll
  for (int i = 1; i < 8; ++i) {
    qn2 = fmaxf(qn2, pool[RED_OFF + i]);
    kn2 = fmaxf(kn2, pool[RED_OFF + 16 + i]);
  }
  float mhat = sqrtf(qn2 * kn2);
  __syncthreads();

  // ---- main pass: wave j covers local q [j*64, j*64+64); lane owns 4 keys ----
  int j = wid, kg = lane;
  float kr[4][8], pjm[4];
  #pragma unroll
  for (int kk = 0; kk < 4; ++kk) {
    #pragma unroll
    for (int dd = 0; dd < 8; ++dd) kr[kk][dd] = pool[KS_OFF + (kk*64+kg)*9 + dd];
    pjm[kk] = ((protok[b*LSEQ + kc*256 + kk*64 + kg] != 0) ? 0.f : -1.0e9f) - mhat;
  }

  float acc[4][8] = {};
  float st = 0.f, mu_sh = -3.0e38f;
  int q0 = j * 64;
  for (int q = q0; q < q0 + 64; ++q) {
    float4 a  = *(const float4*)&pool[QS_OFF + q*8];
    float4 b4 = *(const float4*)&pool[QS_OFF + q*8 + 4];
    float4 c0 = *(const float4*)&pool[VS_OFF + q*8];
    float4 c1 = *(const float4*)&pool[VS_OFF + q*8 + 4];
    float qv[8] = {a.x,a.y,a.z,a.w,b4.x,b4.y,b4.z,b4.w};
    float vv[8] = {c0.x,c0.y,c0.z,c0.w,c1.x,c1.y,c1.z,c1.w};
    #pragma unroll
    for (int kk = 0; kk < 4; ++kk) {
      float d = pjm[kk];
      #pragma unroll
      for (int dd = 0; dd < 8; ++dd) d = fmaf(qv[dd], kr[kk][dd], d);
      mu_sh = fmaxf(mu_sh, d);
      float e = exp2f(d);
      st += e;
      #pragma unroll
      for (int dd = 0; dd < 8; ++dd) acc[kk][dd] = fmaf(e, vv[dd], acc[kk][dd]);
    }
  }
  __syncthreads();

  // block reductions: true max (shifted, log2) and exp-sum
  {
    float mw = wmax64(mu_sh), sw = wsum64(st);
    if (lane == 0) { pool[RED_OFF + wid] = mw; pool[RED_OFF + 16 + wid] = sw; }
  }
  __syncthreads();
  if (t == 0) {
    float m = pool[RED_OFF];
    float s = pool[RED_OFF + 16];
    #pragma unroll
    for (int i = 1; i < 8; ++i) {
      m = fmaxf(m, pool[RED_OFF + i]);
      s += pool[RED_OFF + 16 + i];
    }
    s_out[blk] = s; mh_out[blk] = mhat; mt_out[blk] = m + mhat;
  }
  __syncthreads();

  // ---- merge acc across 8 waves: 3 halving rounds, stride-33 rows ----
#define MWRITE(DW) { _Pragma("unroll") for (int kk = 0; kk < 4; ++kk) \
    { _Pragma("unroll") for (int dd = 0; dd < 8; ++dd) \
      pool[(DW)*2112 + kg*33 + kk*8 + dd] = acc[kk][dd]; } }
#define MADD(SW) { _Pragma("unroll") for (int kk = 0; kk < 4; ++kk) \
    { _Pragma("unroll") for (int dd = 0; dd < 8; ++dd) \
      acc[kk][dd] += pool[(SW)*2112 + kg*33 + kk*8 + dd]; } }
  if (j >= 4) MWRITE(j - 4);
  __syncthreads();
  if (j < 4) MADD(j);
  __syncthreads();
  if (j == 2 || j == 3) MWRITE(j - 2);
  __syncthreads();
  if (j < 2) MADD(j);
  __syncthreads();
  if (j == 1) MWRITE(0);
  __syncthreads();
  if (j == 0) {
    MADD(0);
    float* part = qh ? part1 : part0;
    #pragma unroll
    for (int kk = 0; kk < 4; ++kk) {
      float* dst = &part[((size_t)(b*LSEQ + kc*256 + kk*64 + kg))*DM + h*8];
      *(float4*)dst     = make_float4(acc[kk][0], acc[kk][1], acc[kk][2], acc[kk][3]);
      *(float4*)(dst+4) = make_float4(acc[kk][4], acc[kk][5], acc[kk][6], acc[kk][7]);
    }
  }
#undef MWRITE
#undef MADD
}

// ---- combine: per bh over 8 blocks (4 kc x 2 qh); cs[(kc*2+qh)*64 + bh] ----
__global__ void attn_combine(const float* __restrict__ mh, const float* __restrict__ mt,
                             const float* __restrict__ sp, const float* __restrict__ nz,
                             float* __restrict__ cs){
  int bh = threadIdx.x;
  float mhl[8], sl[8];
  float mu = -3.0e38f;
  #pragma unroll
  for (int i = 0; i < 8; ++i) {
    mhl[i] = mh[bh*8+i]; sl[i] = sp[bh*8+i];
    mu = fmaxf(mu, mt[bh*8+i]);
  }
  float S = 0.f;
  #pragma unroll
  for (int i = 0; i < 8; ++i) S += sl[i] * exp2f(mhl[i] - mu);
  float w = nz[bh >> 3] / S;
  float gm = wmax64(w);
  float c = w / gm;
  #pragma unroll
  for (int i = 0; i < 8; ++i) cs[i*64 + bh] = c * exp2f(mhl[i] - mu);
}

// ---- O-proj + residual + LN1; sums two part slabs; writes out1 into part0 ----
__global__ __launch_bounds__(512) void oproj_ln(
    float* part0, const float* __restrict__ part1, const float* __restrict__ cs,
    const float* __restrict__ Wo, const float* __restrict__ bo,
    const float* __restrict__ xin, const float* __restrict__ g,
    const float* __restrict__ be, const int* __restrict__ protok)
{
  int tid = threadIdx.x, rl = tid >> 6, c = tid & 63;
  int r = blockIdx.x * 8 + rl;
  int bh = ((r >> 10) << 3) + (c >> 3);
  int kc = (r >> 8) & 3;
  __shared__ float As[8][64];
  float cs0 = cs[(kc*2)*64 + bh], cs1 = cs[(kc*2+1)*64 + bh];
  As[rl][c] = part0[(size_t)r * DM + c] * cs0 + part1[(size_t)r * DM + c] * cs1;
  __syncthreads();
  float acc = bo[c];
  #pragma unroll
  for (int jj = 0; jj < DM; ++jj) acc = fmaf(As[rl][jj], Wo[jj * DM + c], acc);
  float keep = (protok[r] != 0) ? 1.f : 0.f;
  float v = xin[(size_t)r * DM + c] + acc * keep;
  float mu = wsum64(v) * 0.015625f;
  float d = v - mu;
  float var = wsum64(d * d) * 0.015625f;
  float o = d * rsqrtf(var + 1e-9f) * g[c] + be[c];
  part0[(size_t)r * DM + c] = o * keep;
}

// ---- fused FFN + residual + LN2 ----
__global__ __launch_bounds__(512) void ffn_ln(
    const float* __restrict__ out1,
    const float* __restrict__ W1, const float* __restrict__ b1,
    const float* __restrict__ W2, const float* __restrict__ b2,
    const float* __restrict__ g, const float* __restrict__ be,
    const int* __restrict__ protok, float* __restrict__ xout)
{
  int tid = threadIdx.x, rl = tid >> 6, c = tid & 63;
  int r = blockIdx.x * 8 + rl;
  __shared__ float xs[8][64];
  __shared__ float h1s[8][DFF];
  xs[rl][c] = out1[(size_t)r * DM + c];
  __syncthreads();
  #pragma unroll
  for (int s = 0; s < 4; ++s) {
    int col = c + 64 * s;
    float a = b1[col];
    #pragma unroll
    for (int jj = 0; jj < DM; ++jj) a = fmaf(xs[rl][jj], W1[jj * DFF + col], a);
    h1s[rl][col] = fmaxf(a, 0.f);
  }
  __syncthreads();
  float a2 = b2[c];
  #pragma unroll 8
  for (int jj = 0; jj < DFF; ++jj) a2 = fmaf(h1s[rl][jj], W2[jj * DM + c], a2);
  float keep = (protok[r] != 0) ? 1.f : 0.f;
  float v = xs[rl][c] + a2 * keep;
  float mu = wsum64(v) * 0.015625f;
  float d = v - mu;
  float var = wsum64(d * d) * 0.015625f;
  float o = d * rsqrtf(var + 1e-9f) * g[c] + be[c];
  xout[(size_t)r * DM + c] = o * keep;
}

extern "C" void kernel_launch(void* const* d_in, const int* in_sizes, int n_in,
                              void* d_out, int out_size, void* d_ws, size_t ws_size,
                              hipStream_t stream) {
  const float* x      = (const float*)d_in[0];
  const int*   protok = (const int*)d_in[1];
  const float* Wq = (const float*)d_in[2];  const float* bq = (const float*)d_in[3];
  const float* Wk = (const float*)d_in[4];  const float* bk = (const float*)d_in[5];
  const float* Wv = (const float*)d_in[6];  const float* bv = (const float*)d_in[7];
  const float* Wo = (const float*)d_in[8];  const float* bo = (const float*)d_in[9];
  const float* W1 = (const float*)d_in[10]; const float* b1 = (const float*)d_in[11];
  const float* W2 = (const float*)d_in[12]; const float* b2 = (const float*)d_in[13];
  const float* g1 = (const float*)d_in[14]; const float* be1 = (const float*)d_in[15];
  const float* g2 = (const float*)d_in[16]; const float* be2 = (const float*)d_in[17];

  const size_t N = (size_t)NROW * DM;   // 524288
  float* xf   = (float*)d_ws;           // N   (state after layers 0..2)
  float* po   = xf + N;                 // N   (part qh=0 -> out1, aliased)
  float* p1   = (float*)d_out;          // N   (part qh=1 scratch; final ffn overwrites)
  float* nzb  = po + N;                 // 8
  float* mh   = nzb + 8;                // 512
  float* mt   = mh + 512;               // 512
  float* sp   = mt + 512;               // 512
  float* cs   = sp + 512;               // 512
  // ws use: 2N + ~2K floats ~= 4.2 MB (proven safe)

  nz_kernel<<<NB, 1024, 0, stream>>>(protok, nzb);

  for (int l = 0; l < NLAYER; ++l) {
    const float* Wq_l = Wq + (size_t)l * DM * DM;  const float* bq_l = bq + (size_t)l * DM;
    const float* Wk_l = Wk + (size_t)l * DM * DM;  const float* bk_l = bk + (size_t)l * DM;
    const float* Wv_l = Wv + (size_t)l * DM * DM;  const float* bv_l = bv + (size_t)l * DM;
    const float* Wo_l = Wo + (size_t)l * DM * DM;  const float* bo_l = bo + (size_t)l * DM;
    const float* W1_l = W1 + (size_t)l * DM * DFF; const float* b1_l = b1 + (size_t)l * DFF;
    const float* W2_l = W2 + (size_t)l * DFF * DM; const float* b2_l = b2 + (size_t)l * DM;
    const float* g1_l = g1 + (size_t)l * DM;  const float* be1_l = be1 + (size_t)l * DM;
    const float* g2_l = g2 + (size_t)l * DM;  const float* be2_l = be2 + (size_t)l * DM;

    const float* xin = (l == 0) ? x : xf;
    float* xout = (l == NLAYER - 1) ? (float*)d_out : xf;

    qkv_attn<<<512, 512, 0, stream>>>(xin, protok, Wq_l, bq_l, Wk_l, bk_l, Wv_l, bv_l,
                                      po, p1, mh, mt, sp);
    attn_combine<<<1, 64, 0, stream>>>(mh, mt, sp, nzb, cs);
    oproj_ln<<<NROW / 8, 512, 0, stream>>>(po, p1, cs, Wo_l, bo_l, xin, g1_l, be1_l, protok);
    ffn_ln<<<NROW / 8, 512, 0, stream>>>(po, W1_l, b1_l, W2_l, b2_l, g2_l, be2_l, protok, xout);
  }
}